// Round 1
// baseline (548.920 us; speedup 1.0000x reference)
//
#include <hip/hip_runtime.h>
#include <hip/hip_bf16.h>
#include <stdint.h>

#define S_LEN 2048
#define HID   2048
#define NH    32
#define NKV   8
#define HD    64

typedef __attribute__((ext_vector_type(8))) short bf16x8;
typedef __attribute__((ext_vector_type(4))) float f32x4;

__device__ __forceinline__ short f2bf(float f) {
  __hip_bfloat16 h = __float2bfloat16(f);
  return __builtin_bit_cast(short, h);
}
__device__ __forceinline__ float bf2f(short s) {
  unsigned u = ((unsigned)(unsigned short)s) << 16;
  return __builtin_bit_cast(float, u);
}

// ---------------- cast fp32 -> bf16 ----------------
__global__ void cast_bf16_kernel(const float* __restrict__ in, short* __restrict__ out, int n4) {
  int i = blockIdx.x * blockDim.x + threadIdx.x;
  if (i < n4) {
    float4 v = reinterpret_cast<const float4*>(in)[i];
    short4 o;
    o.x = f2bf(v.x); o.y = f2bf(v.y); o.z = f2bf(v.z); o.w = f2bf(v.w);
    reinterpret_cast<short4*>(out)[i] = o;
  }
}

// ---------------- transpose + cast: in [K][N] f32 -> out [N][K] bf16 ----------------
__global__ void transpose_cast_kernel(const float* __restrict__ in, short* __restrict__ out,
                                      int K, int N) {
  __shared__ float tile[64][65];
  const int k0 = blockIdx.x * 64;
  const int n0 = blockIdx.y * 64;
  const int tn = threadIdx.x & 63;
  const int t4 = threadIdx.x >> 6;
#pragma unroll
  for (int i = 0; i < 16; i++)
    tile[t4 + i * 4][tn] = in[(size_t)(k0 + t4 + i * 4) * N + n0 + tn];
  __syncthreads();
#pragma unroll
  for (int i = 0; i < 16; i++)
    out[(size_t)(n0 + t4 + i * 4) * K + k0 + tn] = f2bf(tile[tn][t4 + i * 4]);
}

// ---------------- concat bias [2048|512|512] ----------------
__global__ void concat_bias_kernel(const float* __restrict__ bq, const float* __restrict__ bk,
                                   const float* __restrict__ bv, float* __restrict__ out) {
  int i = blockIdx.x * blockDim.x + threadIdx.x;
  if (i < 3072) {
    float v = (i < 2048) ? bq[i] : (i < 2560 ? bk[i - 2048] : bv[i - 2560]);
    out[i] = v;
  }
}

// ---------------- RoPE tables: [S][32] cos and sin ----------------
__global__ void rope_table_kernel(float* __restrict__ ctab, float* __restrict__ stab) {
  int i = blockIdx.x * blockDim.x + threadIdx.x;
  if (i < S_LEN * 32) {
    int t = i >> 5, j = i & 31;
    float ang = (float)t * powf(10000.0f, -(float)j / 32.0f);
    ctab[i] = cosf(ang);
    stab[i] = sinf(ang);
  }
}

// ---------------- GEMM: C[M][N] = A[M][K] * Bt[N][K]^T + bias ----------------
// 128x128 tile, BK=64, 4 waves (2x2), reg-staged LDS with XOR swizzle.
template <int F32OUT>
__global__ __launch_bounds__(256) void gemm_bt_kernel(
    const short* __restrict__ A, const short* __restrict__ Bt,
    const float* __restrict__ bias, void* __restrict__ Cv,
    int M, int N, int K) {
  __shared__ short Als[128 * 64];
  __shared__ short Bls[128 * 64];
  const int tid = threadIdx.x;
  const int l = tid & 63, w = tid >> 6;
  const int lg = l >> 4, lc = l & 15;
  const int m0 = blockIdx.x * 128, n0 = blockIdx.y * 128;
  const int wr = w >> 1, wc = w & 1;
  const int NT = K >> 6;

  const f32x4 zero4 = {0.f, 0.f, 0.f, 0.f};
  f32x4 acc[4][4];
#pragma unroll
  for (int i = 0; i < 4; i++)
#pragma unroll
    for (int j = 0; j < 4; j++) acc[i][j] = zero4;

  const int srow = tid >> 3;          // 0..31
  const int kb = (tid & 7) << 4;      // byte offset within 128B row
  const int kbs = kb ^ ((srow & 7) << 4);

  int4 ar[4], br[4];
  auto stage_load = [&](int kt) {
#pragma unroll
    for (int c = 0; c < 4; c++) {
      int row = c * 32 + srow;
      ar[c] = *reinterpret_cast<const int4*>(A + (size_t)(m0 + row) * K + kt * 64 + (kb >> 1));
      br[c] = *reinterpret_cast<const int4*>(Bt + (size_t)(n0 + row) * K + kt * 64 + (kb >> 1));
    }
  };

  stage_load(0);
  for (int kt = 0; kt < NT; kt++) {
    __syncthreads();
#pragma unroll
    for (int c = 0; c < 4; c++) {
      int row = c * 32 + srow;
      *reinterpret_cast<int4*>(reinterpret_cast<char*>(Als) + row * 128 + kbs) = ar[c];
      *reinterpret_cast<int4*>(reinterpret_cast<char*>(Bls) + row * 128 + kbs) = br[c];
    }
    if (kt + 1 < NT) stage_load(kt + 1);
    __syncthreads();
#pragma unroll
    for (int ks = 0; ks < 2; ks++) {
      bf16x8 af[4], bfr[4];
#pragma unroll
      for (int mi = 0; mi < 4; mi++) {
        int row = wr * 64 + mi * 16 + lc;
        af[mi] = *reinterpret_cast<const bf16x8*>(
            reinterpret_cast<char*>(Als) + row * 128 + ((ks * 64 + lg * 16) ^ ((row & 7) << 4)));
      }
#pragma unroll
      for (int nf = 0; nf < 4; nf++) {
        int row = wc * 64 + nf * 16 + lc;
        bfr[nf] = *reinterpret_cast<const bf16x8*>(
            reinterpret_cast<char*>(Bls) + row * 128 + ((ks * 64 + lg * 16) ^ ((row & 7) << 4)));
      }
#pragma unroll
      for (int mi = 0; mi < 4; mi++)
#pragma unroll
        for (int nf = 0; nf < 4; nf++)
          acc[mi][nf] = __builtin_amdgcn_mfma_f32_16x16x32_bf16(af[mi], bfr[nf], acc[mi][nf], 0, 0, 0);
    }
  }
  // epilogue
#pragma unroll
  for (int mi = 0; mi < 4; mi++) {
#pragma unroll
    for (int nf = 0; nf < 4; nf++) {
      int col = n0 + wc * 64 + nf * 16 + lc;
      float bv = bias[col];
#pragma unroll
      for (int r = 0; r < 4; r++) {
        int rowg = m0 + wr * 64 + mi * 16 + lg * 4 + r;
        float v = acc[mi][nf][r] + bv;
        if (F32OUT)
          reinterpret_cast<float*>(Cv)[(size_t)rowg * N + col] = v;
        else
          reinterpret_cast<short*>(Cv)[(size_t)rowg * N + col] = f2bf(v);
      }
    }
  }
}

// ---------------- fused per-head LayerNorm + RoPE ----------------
// In: [S][instride] bf16 at head offset; Out: [nh][S][HD] bf16 (scaled)
__global__ void ln_rope_kernel(const short* __restrict__ In, int instride, int nh_shift,
                               const float* __restrict__ gam, const float* __restrict__ bet,
                               const float* __restrict__ ctab, const float* __restrict__ stab,
                               float scale, short* __restrict__ Out) {
  const int lane = threadIdx.x & 63;
  const int nh = 1 << nh_shift;
  const int nrows = S_LEN << nh_shift;
  int row = (blockIdx.x * blockDim.x + threadIdx.x) >> 6;
  const int step = (gridDim.x * blockDim.x) >> 6;
  const float g = gam[lane], b = bet[lane];
  for (; row < nrows; row += step) {
    const int t = row >> nh_shift;
    const int h = row & (nh - 1);
    float x = bf2f(In[(size_t)t * instride + h * HD + lane]);
    float s = x;
#pragma unroll
    for (int m = 32; m >= 1; m >>= 1) s += __shfl_xor(s, m);
    const float mu = s * (1.0f / 64.0f);
    float d = x - mu;
    float v2 = d * d;
#pragma unroll
    for (int m = 32; m >= 1; m >>= 1) v2 += __shfl_xor(v2, m);
    const float var = v2 * (1.0f / 64.0f);
    float y = d * rsqrtf(var + 1e-5f) * g + b;
    float part = __shfl_xor(y, 32);
    const float c = ctab[t * 32 + (lane & 31)];
    const float sn = stab[t * 32 + (lane & 31)];
    float o = (lane < 32) ? (y * c - part * sn) : (y * c + part * sn);
    Out[((size_t)h * S_LEN + t) * HD + lane] = f2bf(o * scale);
  }
}

// ---------------- V relayout: [t][g*64+d] (stride 3072) -> [g][d][t] ----------------
__global__ void v_relayout_kernel(const short* __restrict__ In, short* __restrict__ Vt) {
  int i = blockIdx.x * blockDim.x + threadIdx.x;  // NKV*HD*S = 1M
  int t = i & (S_LEN - 1);
  int d = (i >> 11) & (HD - 1);
  int gv = i >> 17;
  Vt[i] = In[(size_t)t * 3072 + gv * HD + d];
}

// ---------------- flash attention ----------------
// Q: [NH][S][HD] bf16 (pre-scaled by 0.125), K: [NKV][S][HD], Vt: [NKV][HD][S]
// AO: [S][HID] bf16. Grid (NH, S/64), 256 threads.
__global__ __launch_bounds__(256) void attn_kernel(
    const short* __restrict__ Q, const short* __restrict__ Kk,
    const short* __restrict__ Vt, short* __restrict__ AO) {
  __shared__ short Kls[64 * 64];
  __shared__ short Vls[64 * 64];
  __shared__ short Pls[4][16][72];  // pad to 144B rows (16B aligned)
  const int tid = threadIdx.x;
  const int l = tid & 63, w = tid >> 6;
  const int lg = l >> 4, lc = l & 15;
  const int h = blockIdx.x;
  const int q0 = blockIdx.y * 64;
  const int g = h >> 2;

  bf16x8 qf[2];
  {
    const short* qb = Q + ((size_t)h * S_LEN + q0 + w * 16 + lc) * HD + lg * 8;
    qf[0] = *reinterpret_cast<const bf16x8*>(qb);
    qf[1] = *reinterpret_cast<const bf16x8*>(qb + 32);
  }

  const f32x4 zero4 = {0.f, 0.f, 0.f, 0.f};
  float m_run[4], l_run[4];
  f32x4 oacc[4];
#pragma unroll
  for (int r = 0; r < 4; r++) { m_run[r] = -3.0e38f; l_run[r] = 0.f; }
#pragma unroll
  for (int df = 0; df < 4; df++) oacc[df] = zero4;

  const int srow = tid >> 3;
  const int kb = (tid & 7) << 4;
  const int kbs = kb ^ ((srow & 7) << 4);
  int4 krg[2], vrg[2];
  auto stage_load = [&](int kt) {
#pragma unroll
    for (int c = 0; c < 2; c++) {
      int row = c * 32 + srow;
      krg[c] = *reinterpret_cast<const int4*>(Kk + ((size_t)g * S_LEN + kt * 64 + row) * HD + (kb >> 1));
      vrg[c] = *reinterpret_cast<const int4*>(Vt + ((size_t)g * HD + row) * S_LEN + kt * 64 + (kb >> 1));
    }
  };

  stage_load(0);
  const int NT = S_LEN / 64;
  for (int kt = 0; kt < NT; kt++) {
    __syncthreads();  // previous tile's LDS reads done
#pragma unroll
    for (int c = 0; c < 2; c++) {
      int row = c * 32 + srow;
      *reinterpret_cast<int4*>(reinterpret_cast<char*>(Kls) + row * 128 + kbs) = krg[c];
      *reinterpret_cast<int4*>(reinterpret_cast<char*>(Vls) + row * 128 + kbs) = vrg[c];
    }
    if (kt + 1 < NT) stage_load(kt + 1);
    __syncthreads();  // staged

    // QK^T  (scores pre-scaled via Q)
    f32x4 sc[4];
#pragma unroll
    for (int nf = 0; nf < 4; nf++) {
      sc[nf] = zero4;
#pragma unroll
      for (int ks = 0; ks < 2; ks++) {
        int row = nf * 16 + lc;
        bf16x8 bk = *reinterpret_cast<const bf16x8*>(
            reinterpret_cast<char*>(Kls) + row * 128 + ((ks * 64 + lg * 16) ^ ((row & 7) << 4)));
        sc[nf] = __builtin_amdgcn_mfma_f32_16x16x32_bf16(qf[ks], bk, sc[nf], 0, 0, 0);
      }
    }

    // online softmax (per row = lg*4 + r, reduce over 16 lanes of group)
    float fac[4];
#pragma unroll
    for (int r = 0; r < 4; r++) {
      float pm = fmaxf(fmaxf(sc[0][r], sc[1][r]), fmaxf(sc[2][r], sc[3][r]));
#pragma unroll
      for (int m = 8; m >= 1; m >>= 1) pm = fmaxf(pm, __shfl_xor(pm, m));
      float mn = fmaxf(m_run[r], pm);
      fac[r] = __expf(m_run[r] - mn);
      m_run[r] = mn;
      float ps = 0.f;
#pragma unroll
      for (int nf = 0; nf < 4; nf++) {
        float p = __expf(sc[nf][r] - mn);
        sc[nf][r] = p;
        ps += p;
      }
#pragma unroll
      for (int m = 8; m >= 1; m >>= 1) ps += __shfl_xor(ps, m);
      l_run[r] = l_run[r] * fac[r] + ps;
    }
#pragma unroll
    for (int df = 0; df < 4; df++)
#pragma unroll
      for (int r = 0; r < 4; r++) oacc[df][r] *= fac[r];

    // P -> LDS (bf16), per-wave region
#pragma unroll
    for (int nf = 0; nf < 4; nf++)
#pragma unroll
      for (int r = 0; r < 4; r++)
        Pls[w][lg * 4 + r][nf * 16 + lc] = f2bf(sc[nf][r]);
    __syncthreads();

    // PV
    bf16x8 pa[2];
#pragma unroll
    for (int ks = 0; ks < 2; ks++)
      pa[ks] = *reinterpret_cast<const bf16x8*>(&Pls[w][lc][ks * 32 + lg * 8]);
#pragma unroll
    for (int df = 0; df < 4; df++) {
#pragma unroll
      for (int ks = 0; ks < 2; ks++) {
        int row = df * 16 + lc;
        bf16x8 bv = *reinterpret_cast<const bf16x8*>(
            reinterpret_cast<char*>(Vls) + row * 128 + ((ks * 64 + lg * 16) ^ ((row & 7) << 4)));
        oacc[df] = __builtin_amdgcn_mfma_f32_16x16x32_bf16(pa[ks], bv, oacc[df], 0, 0, 0);
      }
    }
  }

  // epilogue
#pragma unroll
  for (int r = 0; r < 4; r++) {
    float inv = 1.0f / l_run[r];
    int t = q0 + w * 16 + lg * 4 + r;
#pragma unroll
    for (int df = 0; df < 4; df++) {
      int d = df * 16 + lc;
      AO[(size_t)t * HID + h * HD + d] = f2bf(oacc[df][r] * inv);
    }
  }
}

// ---------------- launch ----------------
extern "C" void kernel_launch(void* const* d_in, const int* in_sizes, int n_in,
                              void* d_out, int out_size, void* d_ws, size_t ws_size,
                              hipStream_t stream) {
  const float* x  = (const float*)d_in[0];
  const float* Wq = (const float*)d_in[1];
  const float* bq = (const float*)d_in[2];
  const float* Wk = (const float*)d_in[3];
  const float* bk = (const float*)d_in[4];
  const float* Wv = (const float*)d_in[5];
  const float* bv = (const float*)d_in[6];
  const float* Wo = (const float*)d_in[7];
  const float* bo = (const float*)d_in[8];
  const float* qg = (const float*)d_in[9];
  const float* qb = (const float*)d_in[10];
  const float* kg = (const float*)d_in[11];
  const float* kb2 = (const float*)d_in[12];
  float* out = (float*)d_out;

  char* ws = (char*)d_ws;
  size_t off = 0;
  auto alloc = [&](size_t bytes) {
    void* p = ws + off;
    off += (bytes + 255) & ~(size_t)255;
    return p;
  };
  short* xb    = (short*)alloc((size_t)2048 * 2048 * 2);
  short* Wqkvt = (short*)alloc((size_t)3072 * 2048 * 2);
  short* Wot   = (short*)alloc((size_t)2048 * 2048 * 2);
  short* QKVp  = (short*)alloc((size_t)2048 * 3072 * 2);
  short* Qr    = (short*)alloc((size_t)NH * 2048 * 64 * 2);
  short* Kr    = (short*)alloc((size_t)NKV * 2048 * 64 * 2);
  short* Vt    = (short*)alloc((size_t)NKV * 64 * 2048 * 2);
  short* AO    = (short*)alloc((size_t)2048 * 2048 * 2);
  float* ctab  = (float*)alloc((size_t)2048 * 32 * 4);
  float* stab  = (float*)alloc((size_t)2048 * 32 * 4);
  float* bqkv  = (float*)alloc((size_t)3072 * 4);

  cast_bf16_kernel<<<(2048 * 2048 / 4 + 255) / 256, 256, 0, stream>>>(x, xb, 2048 * 2048 / 4);
  transpose_cast_kernel<<<dim3(32, 32), 256, 0, stream>>>(Wq, Wqkvt, 2048, 2048);
  transpose_cast_kernel<<<dim3(32, 8), 256, 0, stream>>>(Wk, Wqkvt + (size_t)2048 * 2048, 2048, 512);
  transpose_cast_kernel<<<dim3(32, 8), 256, 0, stream>>>(Wv, Wqkvt + (size_t)2560 * 2048, 2048, 512);
  transpose_cast_kernel<<<dim3(32, 32), 256, 0, stream>>>(Wo, Wot, 2048, 2048);
  concat_bias_kernel<<<12, 256, 0, stream>>>(bq, bk, bv, bqkv);
  rope_table_kernel<<<256, 256, 0, stream>>>(ctab, stab);

  gemm_bt_kernel<0><<<dim3(16, 24), 256, 0, stream>>>(xb, Wqkvt, bqkv, QKVp, 2048, 3072, 2048);

  ln_rope_kernel<<<512, 256, 0, stream>>>(QKVp, 3072, 5, qg, qb, ctab, stab, 0.125f, Qr);
  ln_rope_kernel<<<256, 256, 0, stream>>>(QKVp + 2048, 3072, 3, kg, kb2, ctab, stab, 1.0f, Kr);
  v_relayout_kernel<<<4096, 256, 0, stream>>>(QKVp + 2560, Vt);

  attn_kernel<<<dim3(NH, 32), 256, 0, stream>>>(Qr, Kr, Vt, AO);

  gemm_bt_kernel<1><<<dim3(16, 16), 256, 0, stream>>>(AO, Wot, bo, out, 2048, 2048, 2048);
}

// Round 3
// 458.471 us; speedup vs baseline: 1.1973x; 1.1973x over previous
//
#include <hip/hip_runtime.h>
#include <hip/hip_bf16.h>
#include <stdint.h>

#define S_LEN 2048
#define HID   2048
#define NH    32
#define NKV   8
#define HD    64

typedef __attribute__((ext_vector_type(8))) short bf16x8;
typedef __attribute__((ext_vector_type(4))) float f32x4;
typedef __attribute__((ext_vector_type(16))) float f32x16;

__device__ __forceinline__ short f2bf(float f) {
  __hip_bfloat16 h = __float2bfloat16(f);
  return __builtin_bit_cast(short, h);
}
__device__ __forceinline__ float bf2f(short s) {
  unsigned u = ((unsigned)(unsigned short)s) << 16;
  return __builtin_bit_cast(float, u);
}
__device__ __forceinline__ int cvt_pk_bf16(float lo, float hi) {
  int r;
  asm("v_cvt_pk_bf16_f32 %0, %1, %2" : "=v"(r) : "v"(lo), "v"(hi));
  return r;
}

// ---------------- cast fp32 -> bf16 ----------------
__global__ void cast_bf16_kernel(const float* __restrict__ in, short* __restrict__ out, int n4) {
  int i = blockIdx.x * blockDim.x + threadIdx.x;
  if (i < n4) {
    float4 v = reinterpret_cast<const float4*>(in)[i];
    short4 o;
    o.x = f2bf(v.x); o.y = f2bf(v.y); o.z = f2bf(v.z); o.w = f2bf(v.w);
    reinterpret_cast<short4*>(out)[i] = o;
  }
}

// ---------------- transpose + cast: in [K][N] f32 -> out [N][K] bf16 ----------------
__global__ void transpose_cast_kernel(const float* __restrict__ in, short* __restrict__ out,
                                      int K, int N) {
  __shared__ float tile[64][65];
  const int k0 = blockIdx.x * 64;
  const int n0 = blockIdx.y * 64;
  const int tn = threadIdx.x & 63;
  const int t4 = threadIdx.x >> 6;
#pragma unroll
  for (int i = 0; i < 16; i++)
    tile[t4 + i * 4][tn] = in[(size_t)(k0 + t4 + i * 4) * N + n0 + tn];
  __syncthreads();
#pragma unroll
  for (int i = 0; i < 16; i++)
    out[(size_t)(n0 + t4 + i * 4) * K + k0 + tn] = f2bf(tile[tn][t4 + i * 4]);
}

// ---------------- concat bias [2048|512|512] ----------------
__global__ void concat_bias_kernel(const float* __restrict__ bq, const float* __restrict__ bk,
                                   const float* __restrict__ bv, float* __restrict__ out) {
  int i = blockIdx.x * blockDim.x + threadIdx.x;
  if (i < 3072) {
    float v = (i < 2048) ? bq[i] : (i < 2560 ? bk[i - 2048] : bv[i - 2560]);
    out[i] = v;
  }
}

// ---------------- RoPE tables: [S][32] cos and sin ----------------
__global__ void rope_table_kernel(float* __restrict__ ctab, float* __restrict__ stab) {
  int i = blockIdx.x * blockDim.x + threadIdx.x;
  if (i < S_LEN * 32) {
    int t = i >> 5, j = i & 31;
    float ang = (float)t * powf(10000.0f, -(float)j / 32.0f);
    ctab[i] = cosf(ang);
    stab[i] = sinf(ang);
  }
}

// ---------------- GEMM: C[M][N] = A[M][K] * Bt[N][K]^T + bias ----------------
template <int F32OUT>
__global__ __launch_bounds__(256) void gemm_bt_kernel(
    const short* __restrict__ A, const short* __restrict__ Bt,
    const float* __restrict__ bias, void* __restrict__ Cv,
    int M, int N, int K) {
  __shared__ short Als[128 * 64];
  __shared__ short Bls[128 * 64];
  const int tid = threadIdx.x;
  const int l = tid & 63, w = tid >> 6;
  const int lg = l >> 4, lc = l & 15;
  const int m0 = blockIdx.x * 128, n0 = blockIdx.y * 128;
  const int wr = w >> 1, wc = w & 1;
  const int NT = K >> 6;

  const f32x4 zero4 = {0.f, 0.f, 0.f, 0.f};
  f32x4 acc[4][4];
#pragma unroll
  for (int i = 0; i < 4; i++)
#pragma unroll
    for (int j = 0; j < 4; j++) acc[i][j] = zero4;

  const int srow = tid >> 3;
  const int kb = (tid & 7) << 4;
  const int kbs = kb ^ ((srow & 7) << 4);

  int4 ar[4], br[4];
  auto stage_load = [&](int kt) {
#pragma unroll
    for (int c = 0; c < 4; c++) {
      int row = c * 32 + srow;
      ar[c] = *reinterpret_cast<const int4*>(A + (size_t)(m0 + row) * K + kt * 64 + (kb >> 1));
      br[c] = *reinterpret_cast<const int4*>(Bt + (size_t)(n0 + row) * K + kt * 64 + (kb >> 1));
    }
  };

  stage_load(0);
  for (int kt = 0; kt < NT; kt++) {
    __syncthreads();
#pragma unroll
    for (int c = 0; c < 4; c++) {
      int row = c * 32 + srow;
      *reinterpret_cast<int4*>(reinterpret_cast<char*>(Als) + row * 128 + kbs) = ar[c];
      *reinterpret_cast<int4*>(reinterpret_cast<char*>(Bls) + row * 128 + kbs) = br[c];
    }
    if (kt + 1 < NT) stage_load(kt + 1);
    __syncthreads();
#pragma unroll
    for (int ks = 0; ks < 2; ks++) {
      bf16x8 af[4], bfr[4];
#pragma unroll
      for (int mi = 0; mi < 4; mi++) {
        int row = wr * 64 + mi * 16 + lc;
        af[mi] = *reinterpret_cast<const bf16x8*>(
            reinterpret_cast<char*>(Als) + row * 128 + ((ks * 64 + lg * 16) ^ ((row & 7) << 4)));
      }
#pragma unroll
      for (int nf = 0; nf < 4; nf++) {
        int row = wc * 64 + nf * 16 + lc;
        bfr[nf] = *reinterpret_cast<const bf16x8*>(
            reinterpret_cast<char*>(Bls) + row * 128 + ((ks * 64 + lg * 16) ^ ((row & 7) << 4)));
      }
#pragma unroll
      for (int mi = 0; mi < 4; mi++)
#pragma unroll
        for (int nf = 0; nf < 4; nf++)
          acc[mi][nf] = __builtin_amdgcn_mfma_f32_16x16x32_bf16(af[mi], bfr[nf], acc[mi][nf], 0, 0, 0);
    }
  }
#pragma unroll
  for (int mi = 0; mi < 4; mi++) {
#pragma unroll
    for (int nf = 0; nf < 4; nf++) {
      int col = n0 + wc * 64 + nf * 16 + lc;
      float bv = bias[col];
#pragma unroll
      for (int r = 0; r < 4; r++) {
        int rowg = m0 + wr * 64 + mi * 16 + lg * 4 + r;
        float v = acc[mi][nf][r] + bv;
        if (F32OUT)
          reinterpret_cast<float*>(Cv)[(size_t)rowg * N + col] = v;
        else
          reinterpret_cast<short*>(Cv)[(size_t)rowg * N + col] = f2bf(v);
      }
    }
  }
}

// ---------------- fused per-head LayerNorm + RoPE ----------------
__global__ void ln_rope_kernel(const short* __restrict__ In, int instride, int nh_shift,
                               const float* __restrict__ gam, const float* __restrict__ bet,
                               const float* __restrict__ ctab, const float* __restrict__ stab,
                               float scale, short* __restrict__ Out) {
  const int lane = threadIdx.x & 63;
  const int nh = 1 << nh_shift;
  const int nrows = S_LEN << nh_shift;
  int row = (blockIdx.x * blockDim.x + threadIdx.x) >> 6;
  const int step = (gridDim.x * blockDim.x) >> 6;
  const float g = gam[lane], b = bet[lane];
  for (; row < nrows; row += step) {
    const int t = row >> nh_shift;
    const int h = row & (nh - 1);
    float x = bf2f(In[(size_t)t * instride + h * HD + lane]);
    float s = x;
#pragma unroll
    for (int m = 32; m >= 1; m >>= 1) s += __shfl_xor(s, m);
    const float mu = s * (1.0f / 64.0f);
    float d = x - mu;
    float v2 = d * d;
#pragma unroll
    for (int m = 32; m >= 1; m >>= 1) v2 += __shfl_xor(v2, m);
    const float var = v2 * (1.0f / 64.0f);
    float y = d * rsqrtf(var + 1e-5f) * g + b;
    float part = __shfl_xor(y, 32);
    const float c = ctab[t * 32 + (lane & 31)];
    const float sn = stab[t * 32 + (lane & 31)];
    float o = (lane < 32) ? (y * c - part * sn) : (y * c + part * sn);
    Out[((size_t)h * S_LEN + t) * HD + lane] = f2bf(o * scale);
  }
}

// ---------------- V transpose via LDS: [t][3072 stride] -> [g][d][t] ----------------
__global__ void v_transpose_kernel(const short* __restrict__ In, short* __restrict__ Vt) {
  __shared__ short tile[64][66];
  const int g = blockIdx.x;
  const int t0 = blockIdx.y * 64;
  const int lane = threadIdx.x & 63, w = threadIdx.x >> 6;
#pragma unroll
  for (int i = 0; i < 16; i++) {
    int r = i * 4 + w;
    tile[r][lane] = In[(size_t)(t0 + r) * 3072 + g * 64 + lane];
  }
  __syncthreads();
#pragma unroll
  for (int i = 0; i < 16; i++) {
    int d = i * 4 + w;
    Vt[((size_t)g * 64 + d) * 2048 + t0 + lane] = tile[lane][d];
  }
}

// ---------------- flash attention, m214-style 32x32 swapped structure ----------------
// Q: [NH][S][64] bf16 pre-scaled by 0.125*log2(e); K: [NKV][S][64]; Vt: [NKV][64][S]
// AO: [S][HID] bf16. Grid (NH, S/256), 512 threads = 8 warps x QBLK=32.
__global__ __launch_bounds__(512) void attn_kernel(
    const short* __restrict__ Q, const short* __restrict__ Kk,
    const short* __restrict__ Vt, short* __restrict__ AO) {
  __shared__ short Kls[64 * 64];
  __shared__ short Vls[64 * 64];
  const int tid = threadIdx.x;
  const int l = tid & 63;
  const int w = tid >> 6;          // warp 0..7
  const int q31 = l & 31;
  const int h = l >> 5;            // lane half
  const int head = blockIdx.x;
  const int g = head >> 2;
  const int q0 = blockIdx.y * 256 + w * 32;

  // Q B-frags: lane -> Q[q0+q31][ks*16 + h*8 + j]
  bf16x8 qf[4];
  {
    const short* qb = Q + ((size_t)head * S_LEN + q0 + q31) * HD;
#pragma unroll
    for (int ks = 0; ks < 4; ks++)
      qf[ks] = *reinterpret_cast<const bf16x8*>(qb + ks * 16 + h * 8);
  }

  f32x16 oacc[2];
#pragma unroll
  for (int df = 0; df < 2; df++)
#pragma unroll
    for (int r = 0; r < 16; r++) oacc[df][r] = 0.f;
  float m_run = -1e30f, l_run = 0.f;

  // staging: 512 threads cover 64 rows x 128B in one pass each
  const int srow = tid >> 3;
  const int kb = (tid & 7) << 4;
  const int kbs = kb ^ ((srow & 7) << 4);
  int4 kr, vr;
  auto stage_load = [&](int kt) {
    kr = *reinterpret_cast<const int4*>(Kk + ((size_t)g * S_LEN + kt * 64 + srow) * HD + (kb >> 1));
    vr = *reinterpret_cast<const int4*>(Vt + ((size_t)g * HD + srow) * S_LEN + kt * 64 + (kb >> 1));
  };
  stage_load(0);

  const int swz = (l & 7) << 4;
  const char* KB = reinterpret_cast<const char*>(Kls);
  const char* VB = reinterpret_cast<const char*>(Vls);

  for (int kt = 0; kt < S_LEN / 64; kt++) {
    __syncthreads();  // prev tile LDS reads done
    *reinterpret_cast<int4*>(reinterpret_cast<char*>(Kls) + srow * 128 + kbs) = kr;
    *reinterpret_cast<int4*>(reinterpret_cast<char*>(Vls) + srow * 128 + kbs) = vr;
    if (kt + 1 < S_LEN / 64) stage_load(kt + 1);
    __syncthreads();  // staged

    // QK^T swapped: sc[kc] = mfma(K_frag, Q_frag) -> C[k][q], q = lane&31
    f32x16 sc[2];
#pragma unroll
    for (int i = 0; i < 16; i++) { sc[0][i] = 0.f; sc[1][i] = 0.f; }
#pragma unroll
    for (int ks = 0; ks < 4; ks++) {
#pragma unroll
      for (int kc = 0; kc < 2; kc++) {
        int row = kc * 32 + q31;
        bf16x8 kf = *reinterpret_cast<const bf16x8*>(KB + row * 128 + ((ks * 32 + h * 16) ^ swz));
        sc[kc] = __builtin_amdgcn_mfma_f32_32x32x16_bf16(kf, qf[ks], sc[kc], 0, 0, 0);
      }
    }

    // in-register online softmax (log2 domain; scale folded into Q)
    float pm = sc[0][0];
#pragma unroll
    for (int kc = 0; kc < 2; kc++)
#pragma unroll
      for (int r = 0; r < 16; r++) pm = fmaxf(pm, sc[kc][r]);
    pm = fmaxf(pm, __shfl_xor(pm, 32));   // cross-half max (unambiguous regs)
    if (!__all(pm - m_run <= 11.5f)) {    // defer-max (T13)
      float mn = fmaxf(m_run, pm);
      float fac = __builtin_exp2f(m_run - mn);
      l_run *= fac;
#pragma unroll
      for (int df = 0; df < 2; df++)
#pragma unroll
        for (int r = 0; r < 16; r++) oacc[df][r] *= fac;
      m_run = mn;
    }
    float ps = 0.f;
#pragma unroll
    for (int kc = 0; kc < 2; kc++)
#pragma unroll
      for (int r = 0; r < 16; r++) {
        float p = __builtin_exp2f(sc[kc][r] - m_run);
        sc[kc][r] = p;
        ps += p;
      }
    ps += __shfl_xor(ps, 32);             // cross-half sum (unambiguous regs)
    l_run += ps;

    // P(f32, C-layout) -> bf16 A/B-frags via cvt_pk + permlane32_swap (T12)
    bf16x8 pa[4];
#pragma unroll
    for (int c = 0; c < 4; c++) {
      const int b0 = (c & 1) * 8;
      int wa = cvt_pk_bf16(sc[c >> 1][b0 + 0], sc[c >> 1][b0 + 1]);
      int wb = cvt_pk_bf16(sc[c >> 1][b0 + 4], sc[c >> 1][b0 + 5]);
      asm volatile("v_permlane32_swap_b32 %0, %1" : "+v"(wa), "+v"(wb));
      int wc2 = cvt_pk_bf16(sc[c >> 1][b0 + 2], sc[c >> 1][b0 + 3]);
      int wd = cvt_pk_bf16(sc[c >> 1][b0 + 6], sc[c >> 1][b0 + 7]);
      asm volatile("v_permlane32_swap_b32 %0, %1" : "+v"(wc2), "+v"(wd));
      int4 pw;
      pw.x = wa; pw.y = wc2; pw.z = wb; pw.w = wd;
      pa[c] = __builtin_bit_cast(bf16x8, pw);
    }

    // PV as O^T = mfma(V^T, P^T): C[d][q], q = lane&31 (rescale stays lane-local)
#pragma unroll
    for (int df = 0; df < 2; df++) {
#pragma unroll
      for (int c = 0; c < 4; c++) {
        int row = df * 32 + q31;
        bf16x8 vf = *reinterpret_cast<const bf16x8*>(VB + row * 128 + ((c * 32 + h * 16) ^ swz));
        oacc[df] = __builtin_amdgcn_mfma_f32_32x32x16_bf16(vf, pa[c], oacc[df], 0, 0, 0);
      }
    }
  }

  // epilogue: O^T row d = df*32 + 8*rq + (r&3) + 4h, col q = lane&31
  float inv = 1.0f / l_run;
  short* aob = AO + (size_t)(q0 + q31) * HID + head * HD;
#pragma unroll
  for (int df = 0; df < 2; df++) {
#pragma unroll
    for (int rq = 0; rq < 4; rq++) {
      int v0 = cvt_pk_bf16(oacc[df][rq * 4 + 0] * inv, oacc[df][rq * 4 + 1] * inv);
      int v1 = cvt_pk_bf16(oacc[df][rq * 4 + 2] * inv, oacc[df][rq * 4 + 3] * inv);
      int2 st;
      st.x = v0; st.y = v1;
      *reinterpret_cast<int2*>(aob + df * 32 + rq * 8 + h * 4) = st;
    }
  }
}

// ---------------- launch ----------------
extern "C" void kernel_launch(void* const* d_in, const int* in_sizes, int n_in,
                              void* d_out, int out_size, void* d_ws, size_t ws_size,
                              hipStream_t stream) {
  const float* x  = (const float*)d_in[0];
  const float* Wq = (const float*)d_in[1];
  const float* bq = (const float*)d_in[2];
  const float* Wk = (const float*)d_in[3];
  const float* bk = (const float*)d_in[4];
  const float* Wv = (const float*)d_in[5];
  const float* bv = (const float*)d_in[6];
  const float* Wo = (const float*)d_in[7];
  const float* bo = (const float*)d_in[8];
  const float* qg = (const float*)d_in[9];
  const float* qb = (const float*)d_in[10];
  const float* kg = (const float*)d_in[11];
  const float* kb2 = (const float*)d_in[12];
  float* out = (float*)d_out;

  char* ws = (char*)d_ws;
  size_t off = 0;
  auto alloc = [&](size_t bytes) {
    void* p = ws + off;
    off += (bytes + 255) & ~(size_t)255;
    return p;
  };
  short* xb    = (short*)alloc((size_t)2048 * 2048 * 2);
  short* Wqkvt = (short*)alloc((size_t)3072 * 2048 * 2);
  short* Wot   = (short*)alloc((size_t)2048 * 2048 * 2);
  short* QKVp  = (short*)alloc((size_t)2048 * 3072 * 2);
  short* Qr    = (short*)alloc((size_t)NH * 2048 * 64 * 2);
  short* Kr    = (short*)alloc((size_t)NKV * 2048 * 64 * 2);
  short* Vt    = (short*)alloc((size_t)NKV * 64 * 2048 * 2);
  short* AO    = (short*)alloc((size_t)2048 * 2048 * 2);
  float* ctab  = (float*)alloc((size_t)2048 * 32 * 4);
  float* stab  = (float*)alloc((size_t)2048 * 32 * 4);
  float* bqkv  = (float*)alloc((size_t)3072 * 4);

  cast_bf16_kernel<<<(2048 * 2048 / 4 + 255) / 256, 256, 0, stream>>>(x, xb, 2048 * 2048 / 4);
  transpose_cast_kernel<<<dim3(32, 32), 256, 0, stream>>>(Wq, Wqkvt, 2048, 2048);
  transpose_cast_kernel<<<dim3(32, 8), 256, 0, stream>>>(Wk, Wqkvt + (size_t)2048 * 2048, 2048, 512);
  transpose_cast_kernel<<<dim3(32, 8), 256, 0, stream>>>(Wv, Wqkvt + (size_t)2560 * 2048, 2048, 512);
  transpose_cast_kernel<<<dim3(32, 32), 256, 0, stream>>>(Wo, Wot, 2048, 2048);
  concat_bias_kernel<<<12, 256, 0, stream>>>(bq, bk, bv, bqkv);
  rope_table_kernel<<<256, 256, 0, stream>>>(ctab, stab);

  gemm_bt_kernel<0><<<dim3(16, 24), 256, 0, stream>>>(xb, Wqkvt, bqkv, QKVp, 2048, 3072, 2048);

  // Q pre-scale = 1/sqrt(64) * log2(e)  (softmax runs in exp2 domain)
  ln_rope_kernel<<<512, 256, 0, stream>>>(QKVp, 3072, 5, qg, qb, ctab, stab, 0.125f * 1.44269504089f, Qr);
  ln_rope_kernel<<<256, 256, 0, stream>>>(QKVp + 2048, 3072, 3, kg, kb2, ctab, stab, 1.0f, Kr);
  v_transpose_kernel<<<dim3(8, 32), 256, 0, stream>>>(QKVp + 2560, Vt);

  attn_kernel<<<dim3(NH, 8), 512, 0, stream>>>(Qr, Kr, Vt, AO);

  gemm_bt_kernel<1><<<dim3(16, 16), 256, 0, stream>>>(AO, Wot, bo, out, 2048, 2048, 2048);
}

// Round 4
// 316.526 us; speedup vs baseline: 1.7342x; 1.4484x over previous
//
#include <hip/hip_runtime.h>
#include <hip/hip_bf16.h>
#include <stdint.h>

#define S_LEN 2048
#define HID   2048
#define NH    32
#define NKV   8
#define HD    64

typedef __attribute__((ext_vector_type(8))) short bf16x8;
typedef __attribute__((ext_vector_type(4))) float f32x4;
typedef __attribute__((ext_vector_type(16))) float f32x16;

__device__ __forceinline__ short f2bf(float f) {
  __hip_bfloat16 h = __float2bfloat16(f);
  return __builtin_bit_cast(short, h);
}
__device__ __forceinline__ float bf2f(short s) {
  unsigned u = ((unsigned)(unsigned short)s) << 16;
  return __builtin_bit_cast(float, u);
}
__device__ __forceinline__ int cvt_pk_bf16(float lo, float hi) {
  int r;
  asm("v_cvt_pk_bf16_f32 %0, %1, %2" : "=v"(r) : "v"(lo), "v"(hi));
  return r;
}

// ---------------- cast fp32 -> bf16 ----------------
__global__ void cast_bf16_kernel(const float* __restrict__ in, short* __restrict__ out, int n4) {
  int i = blockIdx.x * blockDim.x + threadIdx.x;
  if (i < n4) {
    float4 v = reinterpret_cast<const float4*>(in)[i];
    short4 o;
    o.x = f2bf(v.x); o.y = f2bf(v.y); o.z = f2bf(v.z); o.w = f2bf(v.w);
    reinterpret_cast<short4*>(out)[i] = o;
  }
}

// ---------------- transpose + cast: in [K][N] f32 -> out [N][K] bf16 ----------------
__global__ void transpose_cast_kernel(const float* __restrict__ in, short* __restrict__ out,
                                      int K, int N) {
  __shared__ float tile[64][65];
  const int k0 = blockIdx.x * 64;
  const int n0 = blockIdx.y * 64;
  const int tn = threadIdx.x & 63;
  const int t4 = threadIdx.x >> 6;
#pragma unroll
  for (int i = 0; i < 16; i++)
    tile[t4 + i * 4][tn] = in[(size_t)(k0 + t4 + i * 4) * N + n0 + tn];
  __syncthreads();
#pragma unroll
  for (int i = 0; i < 16; i++)
    out[(size_t)(n0 + t4 + i * 4) * K + k0 + tn] = f2bf(tile[tn][t4 + i * 4]);
}

// ---------------- concat bias [2048|512|512] ----------------
__global__ void concat_bias_kernel(const float* __restrict__ bq, const float* __restrict__ bk,
                                   const float* __restrict__ bv, float* __restrict__ out) {
  int i = blockIdx.x * blockDim.x + threadIdx.x;
  if (i < 3072) {
    float v = (i < 2048) ? bq[i] : (i < 2560 ? bk[i - 2048] : bv[i - 2560]);
    out[i] = v;
  }
}

// ---------------- RoPE tables: [S][32] cos and sin ----------------
__global__ void rope_table_kernel(float* __restrict__ ctab, float* __restrict__ stab) {
  int i = blockIdx.x * blockDim.x + threadIdx.x;
  if (i < S_LEN * 32) {
    int t = i >> 5, j = i & 31;
    float ang = (float)t * powf(10000.0f, -(float)j / 32.0f);
    ctab[i] = cosf(ang);
    stab[i] = sinf(ang);
  }
}

// ---------------- GEMM v2: C[M][N] = A[M][K] * Bt[N][K]^T + bias ----------------
// 64x128 tile, BK=64, 4 waves (2x2), global_load_lds direct staging, LDS dbuf,
// ONE barrier per K-step, XCD-aware swizzle. M must be 2048 (Mt=32). Grid = 32*(N/128).
template <int F32OUT>
__global__ __launch_bounds__(256, 3) void gemm_v2_kernel(
    const short* __restrict__ A, const short* __restrict__ Bt,
    const float* __restrict__ bias, void* __restrict__ Cv,
    int N, int K) {
  __shared__ short Als[2][64 * 64];
  __shared__ short Bls[2][128 * 64];
  const int tid = threadIdx.x;
  const int l = tid & 63, w = tid >> 6;
  const int lg = l >> 4, lc = l & 15;
  const int wr = w >> 1, wc = w & 1;

  // XCD swizzle (bijective: gridDim.x % 8 == 0). n-major linear id so each
  // XCD gets contiguous n-strips -> B L2-resident.
  const int nwg = gridDim.x;
  const int cpx = nwg >> 3;
  const int swz = (blockIdx.x & 7) * cpx + (blockIdx.x >> 3);
  const int m0 = (swz & 31) << 6;   // Mt = 32 tiles of 64
  const int n0 = (swz >> 5) << 7;   // tiles of 128

  const int NT = K >> 6;
  const f32x4 zero4 = {0.f, 0.f, 0.f, 0.f};
  f32x4 acc[2][4];
#pragma unroll
  for (int i = 0; i < 2; i++)
#pragma unroll
    for (int j = 0; j < 4; j++) acc[i][j] = zero4;

  // staging geometry: per wave, per issue: 8 rows x 128B, lane l -> row base+(l>>3), bytes (l&7)*16
  const int lrow = l >> 3;
  const int lcol = (l & 7) << 3;  // shorts

  auto stage = [&](int buf, int kt) {
    const int kofs = kt << 6;
#pragma unroll
    for (int i = 0; i < 2; i++) {
      const short* gsrc = A + (size_t)(m0 + i * 32 + (w << 3) + lrow) * K + kofs + lcol;
      __builtin_amdgcn_global_load_lds(
          (const __attribute__((address_space(1))) unsigned*)gsrc,
          (__attribute__((address_space(3))) unsigned*)(&Als[buf][(i * 32 + (w << 3)) << 6]),
          16, 0, 0);
    }
#pragma unroll
    for (int i = 0; i < 4; i++) {
      const short* gsrc = Bt + (size_t)(n0 + i * 32 + (w << 3) + lrow) * K + kofs + lcol;
      __builtin_amdgcn_global_load_lds(
          (const __attribute__((address_space(1))) unsigned*)gsrc,
          (__attribute__((address_space(3))) unsigned*)(&Bls[buf][(i * 32 + (w << 3)) << 6]),
          16, 0, 0);
    }
  };

  stage(0, 0);
  int cur = 0;
  for (int kt = 0; kt < NT; kt++) {
    __syncthreads();  // drains stage loads for buf[cur] + prev reads of buf[cur^1]
    if (kt + 1 < NT) stage(cur ^ 1, kt + 1);
    const char* AB = reinterpret_cast<const char*>(Als[cur]);
    const char* BB = reinterpret_cast<const char*>(Bls[cur]);
#pragma unroll
    for (int ks = 0; ks < 2; ks++) {
      bf16x8 af[2], bfr[4];
#pragma unroll
      for (int mi = 0; mi < 2; mi++)
        af[mi] = *reinterpret_cast<const bf16x8*>(
            AB + (wr * 32 + mi * 16 + lc) * 128 + ks * 64 + lg * 16);
#pragma unroll
      for (int nf = 0; nf < 4; nf++)
        bfr[nf] = *reinterpret_cast<const bf16x8*>(
            BB + (wc * 64 + nf * 16 + lc) * 128 + ks * 64 + lg * 16);
#pragma unroll
      for (int mi = 0; mi < 2; mi++)
#pragma unroll
        for (int nf = 0; nf < 4; nf++)
          acc[mi][nf] = __builtin_amdgcn_mfma_f32_16x16x32_bf16(af[mi], bfr[nf], acc[mi][nf], 0, 0, 0);
    }
    cur ^= 1;
  }

  // epilogue
#pragma unroll
  for (int mi = 0; mi < 2; mi++) {
#pragma unroll
    for (int nf = 0; nf < 4; nf++) {
      int col = n0 + wc * 64 + nf * 16 + lc;
      float bv = bias[col];
#pragma unroll
      for (int r = 0; r < 4; r++) {
        int rowg = m0 + wr * 32 + mi * 16 + lg * 4 + r;
        float v = acc[mi][nf][r] + bv;
        if (F32OUT)
          reinterpret_cast<float*>(Cv)[(size_t)rowg * N + col] = v;
        else
          reinterpret_cast<short*>(Cv)[(size_t)rowg * N + col] = f2bf(v);
      }
    }
  }
}

// ---------------- fused per-head LayerNorm + RoPE ----------------
__global__ void ln_rope_kernel(const short* __restrict__ In, int instride, int nh_shift,
                               const float* __restrict__ gam, const float* __restrict__ bet,
                               const float* __restrict__ ctab, const float* __restrict__ stab,
                               float scale, short* __restrict__ Out) {
  const int lane = threadIdx.x & 63;
  const int nh = 1 << nh_shift;
  const int nrows = S_LEN << nh_shift;
  int row = (blockIdx.x * blockDim.x + threadIdx.x) >> 6;
  const int step = (gridDim.x * blockDim.x) >> 6;
  const float g = gam[lane], b = bet[lane];
  for (; row < nrows; row += step) {
    const int t = row >> nh_shift;
    const int h = row & (nh - 1);
    float x = bf2f(In[(size_t)t * instride + h * HD + lane]);
    float s = x;
#pragma unroll
    for (int m = 32; m >= 1; m >>= 1) s += __shfl_xor(s, m);
    const float mu = s * (1.0f / 64.0f);
    float d = x - mu;
    float v2 = d * d;
#pragma unroll
    for (int m = 32; m >= 1; m >>= 1) v2 += __shfl_xor(v2, m);
    const float var = v2 * (1.0f / 64.0f);
    float y = d * rsqrtf(var + 1e-5f) * g + b;
    float part = __shfl_xor(y, 32);
    const float c = ctab[t * 32 + (lane & 31)];
    const float sn = stab[t * 32 + (lane & 31)];
    float o = (lane < 32) ? (y * c - part * sn) : (y * c + part * sn);
    Out[((size_t)h * S_LEN + t) * HD + lane] = f2bf(o * scale);
  }
}

// ---------------- V transpose via LDS: [t][3072 stride] -> [g][d][t] ----------------
__global__ void v_transpose_kernel(const short* __restrict__ In, short* __restrict__ Vt) {
  __shared__ short tile[64][66];
  const int g = blockIdx.x;
  const int t0 = blockIdx.y * 64;
  const int lane = threadIdx.x & 63, w = threadIdx.x >> 6;
#pragma unroll
  for (int i = 0; i < 16; i++) {
    int r = i * 4 + w;
    tile[r][lane] = In[(size_t)(t0 + r) * 3072 + g * 64 + lane];
  }
  __syncthreads();
#pragma unroll
  for (int i = 0; i < 16; i++) {
    int d = i * 4 + w;
    Vt[((size_t)g * 64 + d) * 2048 + t0 + lane] = tile[lane][d];
  }
}

// ---------------- flash attention, m214-style 32x32 swapped structure ----------------
// Q: [NH][S][64] bf16 pre-scaled by 0.125*log2(e); K: [NKV][S][64]; Vt: [NKV][64][S]
// AO: [S][HID] bf16. Grid (NH, S/256), 512 threads = 8 warps x QBLK=32.
__global__ __launch_bounds__(512) void attn_kernel(
    const short* __restrict__ Q, const short* __restrict__ Kk,
    const short* __restrict__ Vt, short* __restrict__ AO) {
  __shared__ short Kls[64 * 64];
  __shared__ short Vls[64 * 64];
  const int tid = threadIdx.x;
  const int l = tid & 63;
  const int w = tid >> 6;          // warp 0..7
  const int q31 = l & 31;
  const int h = l >> 5;            // lane half
  const int head = blockIdx.x;
  const int g = head >> 2;
  const int q0 = blockIdx.y * 256 + w * 32;

  // Q B-frags: lane -> Q[q0+q31][ks*16 + h*8 + j]
  bf16x8 qf[4];
  {
    const short* qb = Q + ((size_t)head * S_LEN + q0 + q31) * HD;
#pragma unroll
    for (int ks = 0; ks < 4; ks++)
      qf[ks] = *reinterpret_cast<const bf16x8*>(qb + ks * 16 + h * 8);
  }

  f32x16 oacc[2];
#pragma unroll
  for (int df = 0; df < 2; df++)
#pragma unroll
    for (int r = 0; r < 16; r++) oacc[df][r] = 0.f;
  float m_run = -1e30f, l_run = 0.f;

  // staging: 512 threads cover 64 rows x 128B in one pass each
  const int srow = tid >> 3;
  const int kb = (tid & 7) << 4;
  const int kbs = kb ^ ((srow & 7) << 4);
  int4 kr, vr;
  auto stage_load = [&](int kt) {
    kr = *reinterpret_cast<const int4*>(Kk + ((size_t)g * S_LEN + kt * 64 + srow) * HD + (kb >> 1));
    vr = *reinterpret_cast<const int4*>(Vt + ((size_t)g * HD + srow) * S_LEN + kt * 64 + (kb >> 1));
  };
  stage_load(0);

  const int swz = (l & 7) << 4;
  const char* KB = reinterpret_cast<const char*>(Kls);
  const char* VB = reinterpret_cast<const char*>(Vls);

  for (int kt = 0; kt < S_LEN / 64; kt++) {
    __syncthreads();  // prev tile LDS reads done
    *reinterpret_cast<int4*>(reinterpret_cast<char*>(Kls) + srow * 128 + kbs) = kr;
    *reinterpret_cast<int4*>(reinterpret_cast<char*>(Vls) + srow * 128 + kbs) = vr;
    if (kt + 1 < S_LEN / 64) stage_load(kt + 1);
    __syncthreads();  // staged

    // QK^T swapped: sc[kc] = mfma(K_frag, Q_frag) -> C[k][q], q = lane&31
    f32x16 sc[2];
#pragma unroll
    for (int i = 0; i < 16; i++) { sc[0][i] = 0.f; sc[1][i] = 0.f; }
#pragma unroll
    for (int ks = 0; ks < 4; ks++) {
#pragma unroll
      for (int kc = 0; kc < 2; kc++) {
        int row = kc * 32 + q31;
        bf16x8 kf = *reinterpret_cast<const bf16x8*>(KB + row * 128 + ((ks * 32 + h * 16) ^ swz));
        sc[kc] = __builtin_amdgcn_mfma_f32_32x32x16_bf16(kf, qf[ks], sc[kc], 0, 0, 0);
      }
    }

    // in-register online softmax (log2 domain; scale folded into Q)
    float pm = sc[0][0];
#pragma unroll
    for (int kc = 0; kc < 2; kc++)
#pragma unroll
      for (int r = 0; r < 16; r++) pm = fmaxf(pm, sc[kc][r]);
    pm = fmaxf(pm, __shfl_xor(pm, 32));   // cross-half max
    if (!__all(pm - m_run <= 11.5f)) {    // defer-max (T13)
      float mn = fmaxf(m_run, pm);
      float fac = __builtin_exp2f(m_run - mn);
      l_run *= fac;
#pragma unroll
      for (int df = 0; df < 2; df++)
#pragma unroll
        for (int r = 0; r < 16; r++) oacc[df][r] *= fac;
      m_run = mn;
    }
    float ps = 0.f;
#pragma unroll
    for (int kc = 0; kc < 2; kc++)
#pragma unroll
      for (int r = 0; r < 16; r++) {
        float p = __builtin_exp2f(sc[kc][r] - m_run);
        sc[kc][r] = p;
        ps += p;
      }
    ps += __shfl_xor(ps, 32);             // cross-half sum
    l_run += ps;

    // P(f32, C-layout) -> bf16 A/B-frags via cvt_pk + permlane32_swap (T12)
    bf16x8 pa[4];
#pragma unroll
    for (int c = 0; c < 4; c++) {
      const int b0 = (c & 1) * 8;
      int wa = cvt_pk_bf16(sc[c >> 1][b0 + 0], sc[c >> 1][b0 + 1]);
      int wb = cvt_pk_bf16(sc[c >> 1][b0 + 4], sc[c >> 1][b0 + 5]);
      asm volatile("v_permlane32_swap_b32 %0, %1" : "+v"(wa), "+v"(wb));
      int wc2 = cvt_pk_bf16(sc[c >> 1][b0 + 2], sc[c >> 1][b0 + 3]);
      int wd = cvt_pk_bf16(sc[c >> 1][b0 + 6], sc[c >> 1][b0 + 7]);
      asm volatile("v_permlane32_swap_b32 %0, %1" : "+v"(wc2), "+v"(wd));
      int4 pw;
      pw.x = wa; pw.y = wc2; pw.z = wb; pw.w = wd;
      pa[c] = __builtin_bit_cast(bf16x8, pw);
    }

    // PV as O^T = mfma(V^T, P^T): C[d][q], q = lane&31 (rescale stays lane-local)
#pragma unroll
    for (int df = 0; df < 2; df++) {
#pragma unroll
      for (int c = 0; c < 4; c++) {
        int row = df * 32 + q31;
        bf16x8 vf = *reinterpret_cast<const bf16x8*>(VB + row * 128 + ((c * 32 + h * 16) ^ swz));
        oacc[df] = __builtin_amdgcn_mfma_f32_32x32x16_bf16(vf, pa[c], oacc[df], 0, 0, 0);
      }
    }
  }

  // epilogue: O^T row d = df*32 + 8*rq + (r&3) + 4h, col q = lane&31
  float inv = 1.0f / l_run;
  short* aob = AO + (size_t)(q0 + q31) * HID + head * HD;
#pragma unroll
  for (int df = 0; df < 2; df++) {
#pragma unroll
    for (int rq = 0; rq < 4; rq++) {
      int v0 = cvt_pk_bf16(oacc[df][rq * 4 + 0] * inv, oacc[df][rq * 4 + 1] * inv);
      int v1 = cvt_pk_bf16(oacc[df][rq * 4 + 2] * inv, oacc[df][rq * 4 + 3] * inv);
      int2 st;
      st.x = v0; st.y = v1;
      *reinterpret_cast<int2*>(aob + df * 32 + rq * 8 + h * 4) = st;
    }
  }
}

// ---------------- launch ----------------
extern "C" void kernel_launch(void* const* d_in, const int* in_sizes, int n_in,
                              void* d_out, int out_size, void* d_ws, size_t ws_size,
                              hipStream_t stream) {
  const float* x  = (const float*)d_in[0];
  const float* Wq = (const float*)d_in[1];
  const float* bq = (const float*)d_in[2];
  const float* Wk = (const float*)d_in[3];
  const float* bk = (const float*)d_in[4];
  const float* Wv = (const float*)d_in[5];
  const float* bv = (const float*)d_in[6];
  const float* Wo = (const float*)d_in[7];
  const float* bo = (const float*)d_in[8];
  const float* qg = (const float*)d_in[9];
  const float* qb = (const float*)d_in[10];
  const float* kg = (const float*)d_in[11];
  const float* kb2 = (const float*)d_in[12];
  float* out = (float*)d_out;

  char* ws = (char*)d_ws;
  size_t off = 0;
  auto alloc = [&](size_t bytes) {
    void* p = ws + off;
    off += (bytes + 255) & ~(size_t)255;
    return p;
  };
  short* xb    = (short*)alloc((size_t)2048 * 2048 * 2);
  short* Wqkvt = (short*)alloc((size_t)3072 * 2048 * 2);
  short* Wot   = (short*)alloc((size_t)2048 * 2048 * 2);
  short* QKVp  = (short*)alloc((size_t)2048 * 3072 * 2);
  short* Qr    = (short*)alloc((size_t)NH * 2048 * 64 * 2);
  short* Kr    = (short*)alloc((size_t)NKV * 2048 * 64 * 2);
  short* Vt    = (short*)alloc((size_t)NKV * 64 * 2048 * 2);
  short* AO    = (short*)alloc((size_t)2048 * 2048 * 2);
  float* ctab  = (float*)alloc((size_t)2048 * 32 * 4);
  float* stab  = (float*)alloc((size_t)2048 * 32 * 4);
  float* bqkv  = (float*)alloc((size_t)3072 * 4);

  cast_bf16_kernel<<<(2048 * 2048 / 4 + 255) / 256, 256, 0, stream>>>(x, xb, 2048 * 2048 / 4);
  transpose_cast_kernel<<<dim3(32, 32), 256, 0, stream>>>(Wq, Wqkvt, 2048, 2048);
  transpose_cast_kernel<<<dim3(32, 8), 256, 0, stream>>>(Wk, Wqkvt + (size_t)2048 * 2048, 2048, 512);
  transpose_cast_kernel<<<dim3(32, 8), 256, 0, stream>>>(Wv, Wqkvt + (size_t)2560 * 2048, 2048, 512);
  transpose_cast_kernel<<<dim3(32, 32), 256, 0, stream>>>(Wo, Wot, 2048, 2048);
  concat_bias_kernel<<<12, 256, 0, stream>>>(bq, bk, bv, bqkv);
  rope_table_kernel<<<256, 256, 0, stream>>>(ctab, stab);

  // QKV: M=2048 (Mt=32), N=3072 -> grid 32*24 = 768 blocks (768 % 8 == 0)
  gemm_v2_kernel<0><<<768, 256, 0, stream>>>(xb, Wqkvt, bqkv, QKVp, 3072, 2048);

  // Q pre-scale = 1/sqrt(64) * log2(e)  (softmax runs in exp2 domain)
  ln_rope_kernel<<<512, 256, 0, stream>>>(QKVp, 3072, 5, qg, qb, ctab, stab, 0.125f * 1.44269504089f, Qr);
  ln_rope_kernel<<<256, 256, 0, stream>>>(QKVp + 2048, 3072, 3, kg, kb2, ctab, stab, 1.0f, Kr);
  v_transpose_kernel<<<dim3(8, 32), 256, 0, stream>>>(QKVp + 2560, Vt);

  attn_kernel<<<dim3(NH, 8), 512, 0, stream>>>(Qr, Kr, Vt, AO);

  // Out-proj: M=2048, N=2048 -> grid 32*16 = 512 blocks
  gemm_v2_kernel<1><<<512, 256, 0, stream>>>(AO, Wot, bo, out, 2048, 2048);
}